// Round 5
// baseline (107.591 us; speedup 1.0000x reference)
//
#include <hip/hip_runtime.h>
#include <stdint.h>
#include <math.h>

// Multiresolution hash encoding, 16 levels.
// grids = {4,5,6,9,12,15,21,27,36,48,63,84,111,147,194,255}
// kh = 256//grid, P = floor(256/kh).
// K1 (fused): levels 0..12 pooling+table-gather into dense fws (float3/cell)
//             PLUS levels 13..15 (kh=1: bilinear=identity) direct hash->out.
//             Independent work, concurrent blocks, one launch.
// K2: levels 0..12 bilinear upsample reading fws directly via L1/L2 (no LDS),
//     4 px/thread, float4 stores.

#define NLVL 16
#define NB   16

__constant__ int   c_P[NLVL]   = {4,5,6,9,12,15,21,28,36,51,64,85,128,256,256,256};
__constant__ int   c_KH[NLVL]  = {64,51,42,28,21,17,12,9,7,5,4,3,2,1,1,1};
__constant__ float c_G[NLVL]   = {4.f,5.f,6.f,9.f,12.f,15.f,21.f,27.f,36.f,48.f,63.f,84.f,111.f,147.f,194.f,255.f};
// prefix sums of P^2 for levels 0..12 (cells per batch), total 33354
__constant__ int   c_CUM[14]   = {0,16,41,77,158,302,527,968,1752,3048,5649,9745,16970,33354};

#define A_LVLS    9        // levels 0..8: wave-per-cell
#define A_CELLS   3048     // cells/batch, levels 0..8
#define A_BLOCKS  12192    // A_CELLS*16/4
#define B2_FIRST  9        // levels 9..12: thread-per-cell
#define B2_CELLS  30306    // 33354 - 3048
#define B2_THREADS (B2_CELLS*NB)            // 484896
#define B2_BLOCKS ((B2_THREADS + 255)/256)  // 1895
#define PD_FIRST  (A_BLOCKS + B2_BLOCKS)    // 14087
#define PD_BLOCKS 1024
#define K1_BLOCKS (PD_FIRST + PD_BLOCKS)    // 15111

__device__ __forceinline__ uint32_t hash3(float m0, float m1, float m2, float g) {
    uint32_t v0 = (uint32_t)(int)(m0 * g);
    uint32_t v1 = (uint32_t)(int)(m1 * g);
    uint32_t v2 = (uint32_t)(int)(m2 * g);
    return (v0 ^ (v1 * 2654435761u) ^ (v2 * 805459861u)) & 0xFFFFu;
}

// ---- K1: fused pooling (levels 0..12 -> fws) + direct levels 13..15 -> out
__global__ __launch_bounds__(256) void pool_fused(const float* __restrict__ img,
                                                  const float* __restrict__ tab,
                                                  float* __restrict__ fws,
                                                  float* __restrict__ out)
{
    if (blockIdx.x < A_BLOCKS) {
        // wave path, levels 0..8: 2D lane map (col = lane%kh, row-group = lane/kh)
        int wid  = blockIdx.x * 4 + (threadIdx.x >> 6);
        int lane = threadIdx.x & 63;
        int b = wid / A_CELLS;
        int r = wid - b * A_CELLS;
        int lvl = 0;
#pragma unroll
        for (int l = 1; l < A_LVLS; ++l) lvl += (r >= c_CUM[l]);
        int P = c_P[lvl], kh = c_KH[lvl];
        int cell = r - c_CUM[lvl];
        int iy = cell / P, ix = cell - iy * P;

        int G   = 64 / kh;
        int col = lane % kh;
        int grp = lane / kh;

        float m0 = -INFINITY, m1 = -INFINITY, m2 = -INFINITY;
        if (grp < G) {
            const float* p = img + (size_t)b * 196608 + (size_t)(iy * kh) * 256 + ix * kh + col;
            for (int rr = grp; rr < kh; rr += G) {
                int o = rr * 256;
                m0 = fmaxf(m0, p[o]);
                m1 = fmaxf(m1, p[65536 + o]);
                m2 = fmaxf(m2, p[131072 + o]);
            }
        }
#pragma unroll
        for (int off = 32; off > 0; off >>= 1) {
            m0 = fmaxf(m0, __shfl_xor(m0, off, 64));
            m1 = fmaxf(m1, __shfl_xor(m1, off, 64));
            m2 = fmaxf(m2, __shfl_xor(m2, off, 64));
        }
        if (lane == 0) {
            uint32_t gg = hash3(m0, m1, m2, c_G[lvl]);
            const float* T = tab + (size_t)lvl * 196608 + gg * 3;
            float* f = fws + ((size_t)c_CUM[lvl] * NB + (size_t)b * (P * P) + cell) * 3;
            f[0] = T[0]; f[1] = T[1]; f[2] = T[2];
        }
    } else if (blockIdx.x < PD_FIRST) {
        // thread path, levels 9..12 (kh <= 5)
        int tid = (blockIdx.x - A_BLOCKS) * 256 + threadIdx.x;
        if (tid >= B2_THREADS) return;
        int b = tid / B2_CELLS;
        int r = tid - b * B2_CELLS + A_CELLS;
        int lvl = B2_FIRST;
#pragma unroll
        for (int l = B2_FIRST + 1; l <= 12; ++l) lvl += (r >= c_CUM[l]);
        int P = c_P[lvl], kh = c_KH[lvl];
        int cell = r - c_CUM[lvl];
        int iy = cell / P, ix = cell - iy * P;

        const float* p = img + (size_t)b * 196608 + (size_t)(iy * kh) * 256 + ix * kh;
        float m0 = -INFINITY, m1 = -INFINITY, m2 = -INFINITY;
        for (int rr = 0; rr < kh; ++rr)
            for (int cc = 0; cc < kh; ++cc) {
                int o = rr * 256 + cc;
                m0 = fmaxf(m0, p[o]);
                m1 = fmaxf(m1, p[65536 + o]);
                m2 = fmaxf(m2, p[131072 + o]);
            }
        uint32_t gg = hash3(m0, m1, m2, c_G[lvl]);
        const float* T = tab + (size_t)lvl * 196608 + gg * 3;
        float* f = fws + ((size_t)c_CUM[lvl] * NB + (size_t)b * (P * P) + cell) * 3;
        f[0] = T[0]; f[1] = T[1]; f[2] = T[2];
    } else {
        // direct path, levels 13..15: identity bilinear, 4 px/thread
        int t = (blockIdx.x - PD_FIRST) * 256 + threadIdx.x;   // 262144 total
        int b = t >> 14;
        int pix0 = (t & 16383) << 2;
        const float* p = img + (size_t)b * 196608 + pix0;
        float4 i0 = *(const float4*)p;
        float4 i1 = *(const float4*)(p + 65536);
        float4 i2 = *(const float4*)(p + 131072);
#pragma unroll
        for (int lvl = 13; lvl < 16; ++lvl) {
            float g = c_G[lvl];
            const float* T = tab + (size_t)lvl * 196608;
            uint32_t g0 = hash3(i0.x, i1.x, i2.x, g);
            uint32_t g1 = hash3(i0.y, i1.y, i2.y, g);
            uint32_t g2 = hash3(i0.z, i1.z, i2.z, g);
            uint32_t g3 = hash3(i0.w, i1.w, i2.w, g);
            float4 o0, o1, o2;
            o0.x = T[g0*3];   o1.x = T[g0*3+1]; o2.x = T[g0*3+2];
            o0.y = T[g1*3];   o1.y = T[g1*3+1]; o2.y = T[g1*3+2];
            o0.z = T[g2*3];   o1.z = T[g2*3+1]; o2.z = T[g2*3+2];
            o0.w = T[g3*3];   o1.w = T[g3*3+1]; o2.w = T[g3*3+2];
            float* ob = out + ((size_t)b * 48 + 3 * lvl) * 65536 + pix0;
            *(float4*)ob            = o0;
            *(float4*)(ob + 65536)  = o1;
            *(float4*)(ob + 131072) = o2;
        }
    }
}

// ---- K2: levels 0..12 bilinear upsample, direct global reads, 4 px/thread
// src = ((2o+1)*P - 256)/512 : exact int; frac exact in fp32.
__global__ __launch_bounds__(256) void upsample4(const float* __restrict__ fws,
                                                 float* __restrict__ out)
{
    int plane = blockIdx.y;          // lvl*16 + b, lvl in [0,13)
    int lvl   = plane >> 4;
    int b     = plane & 15;
    int P     = c_P[lvl];

    int w    = threadIdx.x >> 6;
    int lane = threadIdx.x & 63;
    int y    = blockIdx.x * 4 + w;

    int numy = (2 * y + 1) * P - 256;
    int iy0  = numy >> 9;
    float fy = (float)(numy & 511) * (1.0f / 512.0f);
    int iy1;
    if (iy0 < 0)           { iy0 = 0;     iy1 = 0;     fy = 0.f; }
    else if (iy0 >= P - 1) { iy0 = P - 1; iy1 = P - 1; fy = 0.f; }
    else                   { iy1 = iy0 + 1; }

    const float* fb = fws + ((size_t)c_CUM[lvl] * NB + (size_t)b * P * P) * 3;
    const float* r0 = fb + (size_t)iy0 * P * 3;
    const float* r1 = fb + (size_t)iy1 * P * 3;
    float wy0 = 1.f - fy, wy1 = fy;

    float v[3][4];
    int xb = lane << 2;
#pragma unroll
    for (int j = 0; j < 4; ++j) {
        int numx = (2 * (xb + j) + 1) * P - 256;
        int ix0  = numx >> 9;
        float fx = (float)(numx & 511) * (1.0f / 512.0f);
        int ix1;
        if (ix0 < 0)           { ix0 = 0;     ix1 = 0;     fx = 0.f; }
        else if (ix0 >= P - 1) { ix0 = P - 1; ix1 = P - 1; fx = 0.f; }
        else                   { ix1 = ix0 + 1; }
        float wx0 = 1.f - fx, wx1 = fx;
        float3 t00 = *(const float3*)(r0 + ix0 * 3);
        float3 t01 = *(const float3*)(r0 + ix1 * 3);
        float3 t10 = *(const float3*)(r1 + ix0 * 3);
        float3 t11 = *(const float3*)(r1 + ix1 * 3);
        v[0][j] = wy0 * (wx0 * t00.x + wx1 * t01.x) + wy1 * (wx0 * t10.x + wx1 * t11.x);
        v[1][j] = wy0 * (wx0 * t00.y + wx1 * t01.y) + wy1 * (wx0 * t10.y + wx1 * t11.y);
        v[2][j] = wy0 * (wx0 * t00.z + wx1 * t01.z) + wy1 * (wx0 * t10.z + wx1 * t11.z);
    }
    float* o = out + ((size_t)b * 48 + 3 * lvl) * 65536 + (size_t)y * 256 + xb;
#pragma unroll
    for (int c = 0; c < 3; ++c) {
        float4 q; q.x = v[c][0]; q.y = v[c][1]; q.z = v[c][2]; q.w = v[c][3];
        *(float4*)(o + (size_t)c * 65536) = q;
    }
}

extern "C" void kernel_launch(void* const* d_in, const int* in_sizes, int n_in,
                              void* d_out, int out_size, void* d_ws, size_t ws_size,
                              hipStream_t stream)
{
    const float* img = (const float*)d_in[0];   // (16,3,256,256) f32
    const float* tab = (const float*)d_in[1];   // (16,65536,3) f32
    float* out = (float*)d_out;                 // (16,48,256,256) f32
    float* fws = (float*)d_ws;                  // 33354*16*3 f32 = 6.4 MB

    hipLaunchKernelGGL(pool_fused, dim3(K1_BLOCKS), dim3(256), 0, stream, img, tab, fws, out);
    hipLaunchKernelGGL(upsample4,  dim3(64, 13 * 16), dim3(256), 0, stream, fws, out);
}